// Round 12
// baseline (1263.960 us; speedup 1.0000x reference)
//
#include <hip/hip_runtime.h>
#include <hip/hip_bf16.h>

#define B_ 8
#define N_ 1024
#define K_ 20
#define BN_ (B_*N_)

// 1/sqrt(1+1e-5)  (eval-mode BN with running_var=1)
#define BN_SCALE 0.9999950000374997f

__device__ __forceinline__ float US2F(unsigned short u) {
    union { unsigned u; float f; } c; c.u = ((unsigned)u) << 16; return c.f;
}

// ---------------------------------------------------------------- dtype detect
__global__ void k_detect(const unsigned short* g1, const unsigned short* g2,
                         const unsigned short* g3, const unsigned short* g4,
                         const unsigned short* g5, const unsigned short* g6,
                         const unsigned short* g7, int* flag) {
    const unsigned short* gs[7] = {g1, g2, g3, g4, g5, g6, g7};
    int cnt = 0;
    for (int i = 0; i < 7; i++) {
        float v = US2F(gs[i][0]);
        if (v > 0.5f && v < 1.5f) cnt++;
    }
    *flag = (cnt >= 4) ? 1 : 0;   // 1 = bf16 inputs, 0 = fp32 inputs
}

// ---------------------------------------------------------------- prep:
// mode 0: transpose (O,I)->(I,O).  mode 1: edge pair — src w(O, I=2C) ->
// dst (C, 2O) with cols [0,O)=wn (i<C) and [O,2O)=wc (i>=C).
struct TPar { const void* src; float* dst; int O, I, blk0, mode; };
struct TList { TPar p[41]; };

__global__ __launch_bounds__(256) void k_prep(TList tl, int nent, const int* flag) {
    const int isbf = *flag;
    int blk = blockIdx.x;
    int wi = 0;
    for (int j = nent - 1; j >= 0; j--) { if (blk >= tl.p[j].blk0) { wi = j; break; } }
    const TPar p = tl.p[wi];
    int e = (blk - p.blk0) * 256 + threadIdx.x;
    int n = p.O * p.I;
    if (e >= n) return;
    int o = e / p.I, i = e - o * p.I;
    float v = isbf ? US2F(((const unsigned short*)p.src)[e])
                   : ((const float*)p.src)[e];
    if (p.mode == 0) {
        p.dst[(size_t)i * p.O + o] = v;
    } else {
        const int C = p.I >> 1;
        if (i < C) p.dst[(size_t)i * (2 * p.O) + o] = v;
        else       p.dst[(size_t)(i - C) * (2 * p.O) + p.O + o] = v;
    }
}

// ---------------------------------------------------------------- norms
__global__ __launch_bounds__(256) void k_norms(const float* __restrict__ xf,
                                               float* __restrict__ xx, int C) {
    int i = blockIdx.x * 256 + threadIdx.x;
    if (i >= BN_) return;
    const float* p = xf + (size_t)i * C;
    float s = 0.f;
    for (int c = 0; c < C; c++) s += p[c] * p[c];
    xx[i] = s;
}

// ---------------------------------------------------------------- kNN phase 1:
// pd[b] = 2 * X_b @ X_b^T. 128x64 tile, 8x4/thread: 32 FMAs per 3 b128 LDS
// reads (the R11 4x4 tile was capped at VALUBusy ~55% by a 16:2 FMA:b128 mix).
template<int C>
__global__ __launch_bounds__(256) void k_pd(const float* __restrict__ xf,
                                            float* __restrict__ pd) {
    const int b = blockIdx.z;
    const int rb = blockIdx.x * 128, cb = blockIdx.y * 64;
    const float* xb = xf + (size_t)b * N_ * C;
    const int t = threadIdx.x;
    __shared__ float As[32][129];   // As[k][m], stride 129 % 32 == 1 (conflict-free staging)
    __shared__ float Bs[32][65];    // Bs[k][j]
    float acc[8][4] = {};
    const int tm = (t >> 4) * 8, tn = (t & 15) * 4;
    for (int k0 = 0; k0 < C; k0 += 32) {
        __syncthreads();
        #pragma unroll
        for (int u = t; u < 128 * 32; u += 256) {
            int m = u >> 5, k = u & 31;
            float v;
            if constexpr (C % 32 == 0) v = xb[(size_t)(rb + m) * C + k0 + k];
            else v = (k0 + k < C) ? xb[(size_t)(rb + m) * C + k0 + k] : 0.f;
            As[k][m] = v;
        }
        #pragma unroll
        for (int u = t; u < 64 * 32; u += 256) {
            int j = u >> 5, k = u & 31;
            float v;
            if constexpr (C % 32 == 0) v = xb[(size_t)(cb + j) * C + k0 + k];
            else v = (k0 + k < C) ? xb[(size_t)(cb + j) * C + k0 + k] : 0.f;
            Bs[k][j] = v;
        }
        __syncthreads();
        #pragma unroll
        for (int k = 0; k < 32; k++) {
            const float4 a0 = *reinterpret_cast<const float4*>(&As[k][tm]);
            const float4 a1 = *reinterpret_cast<const float4*>(&As[k][tm + 4]);
            const float4 bv = *reinterpret_cast<const float4*>(&Bs[k][tn]);
            const float av[8] = {a0.x, a0.y, a0.z, a0.w, a1.x, a1.y, a1.z, a1.w};
            #pragma unroll
            for (int j = 0; j < 8; j++) {
                acc[j][0] += av[j] * bv.x; acc[j][1] += av[j] * bv.y;
                acc[j][2] += av[j] * bv.z; acc[j][3] += av[j] * bv.w;
            }
        }
    }
    float* pdb = pd + (size_t)b * N_ * N_;
    #pragma unroll
    for (int j = 0; j < 8; j++) {
        const int row = rb + tm + j;
        #pragma unroll
        for (int jj = 0; jj < 4; jj++)
            pdb[(size_t)row * N_ + cb + tn + jj] = 2.f * acc[j][jj];
    }
}

// ---------------------------------------------------------------- kNN phase 2:
// wave-per-point top-20 over d[j] = pd[i][j] - xx[j].
__global__ __launch_bounds__(256) void k_sel(const float* __restrict__ pd,
                                             const float* __restrict__ xx,
                                             int* __restrict__ idx) {
    const int w = threadIdx.x >> 6, lane = threadIdx.x & 63;
    const int i = blockIdx.x * 4 + w;          // 0..8191
    const int b = i >> 10;
    const float* row = pd + (size_t)b * N_ * N_ + (size_t)(i & 1023) * N_;
    const float* xxb = xx + b * N_;
    float d[16];
    #pragma unroll
    for (int q = 0; q < 16; q++)
        d[q] = row[q * 64 + lane] - xxb[q * 64 + lane];
    int myj = 0;
    for (int kk = 0; kk < K_; kk++) {
        float v = d[0];
        #pragma unroll
        for (int u = 1; u < 16; u++) v = fmaxf(v, d[u]);
        #pragma unroll
        for (int s = 1; s < 64; s <<= 1) v = fmaxf(v, __shfl_xor(v, s, 64));
        int jw = -1;
        #pragma unroll
        for (int u = 0; u < 16; u++) {
            unsigned long long m = __ballot(d[u] == v);
            if (jw < 0 && m != 0ULL) jw = u * 64 + (int)__ffsll((long long)m) - 1;
        }
        if (jw < 0) jw = 0;                    // unreachable guard
        if (lane == kk) myj = jw;
        const int wq = jw >> 6, wl = jw & 63;
        #pragma unroll
        for (int u = 0; u < 16; u++)
            if (u == wq && lane == wl) d[u] = -3e38f;
    }
    if (lane < K_) idx[(size_t)i * K_ + lane] = myj;
}

// ---------------------------------------------------------------- GEMM
// C[8192][NC] = A[8192][KD] @ Bt[KD][NC] (+bias); optional q-scale, residual,
// BN+lrelu epilogue. 128x64 tile, 8x4/thread (32 FMAs per 3 b128 reads).
template<int KD, int NC>
__global__ __launch_bounds__(256) void k_gemm(const float* __restrict__ A,
                                              const float* __restrict__ Bt,
                                              const float* __restrict__ bias,
                                              const float* __restrict__ resid,
                                              float* __restrict__ Cout,
                                              int scale_cols, float qs,
                                              const float* __restrict__ gamma,
                                              const float* __restrict__ beta) {
    const int t = threadIdx.x;
    const int rb = blockIdx.x * 128;
    const int cb = blockIdx.y * 64;
    __shared__ float As[32][129];   // As[k][m]
    __shared__ float Bs[32][68];
    float acc[8][4] = {};
    const int tm = (t >> 4) * 8, tn = (t & 15) * 4;
    for (int k0 = 0; k0 < KD; k0 += 32) {
        __syncthreads();
        #pragma unroll
        for (int u = t; u < 128 * 32; u += 256) {
            int m = u >> 5, k = u & 31;
            float av;
            if constexpr (KD % 32 == 0) av = A[(size_t)(rb + m) * KD + k0 + k];
            else av = (k0 + k < KD) ? A[(size_t)(rb + m) * KD + k0 + k] : 0.f;
            As[k][m] = av;
        }
        #pragma unroll
        for (int u = t; u < 32 * 64; u += 256) {
            int k = u >> 6, c = u & 63;
            float bvv;
            if constexpr (KD % 32 == 0) bvv = Bt[(size_t)(k0 + k) * NC + cb + c];
            else bvv = (k0 + k < KD) ? Bt[(size_t)(k0 + k) * NC + cb + c] : 0.f;
            Bs[k][c] = bvv;
        }
        __syncthreads();
        #pragma unroll
        for (int k = 0; k < 32; k++) {
            const float4 a0 = *reinterpret_cast<const float4*>(&As[k][tm]);
            const float4 a1 = *reinterpret_cast<const float4*>(&As[k][tm + 4]);
            const float4 bv = *reinterpret_cast<const float4*>(&Bs[k][tn]);
            const float av[8] = {a0.x, a0.y, a0.z, a0.w, a1.x, a1.y, a1.z, a1.w};
            #pragma unroll
            for (int j = 0; j < 8; j++) {
                acc[j][0] += av[j] * bv.x; acc[j][1] += av[j] * bv.y;
                acc[j][2] += av[j] * bv.z; acc[j][3] += av[j] * bv.w;
            }
        }
    }
    #pragma unroll
    for (int j = 0; j < 8; j++) {
        const int row = rb + tm + j;
        #pragma unroll
        for (int jj = 0; jj < 4; jj++) {
            const int col = cb + tn + jj;
            float v = acc[j][jj] + (bias ? bias[col] : 0.f);
            if (col < scale_cols) v *= qs;
            if (resid) v += resid[(size_t)row * NC + col];
            if (gamma) {
                v = v * (gamma[col] * BN_SCALE) + beta[col];
                v = v >= 0.f ? v : 0.2f * v;
            }
            Cout[(size_t)row * NC + col] = v;
        }
    }
}

// ---------------------------------------------------------------- EdgeConv epilogue
// yz rows: [ y(CO) | z(CO) ].  out[i] = lrelu(bn( max_k y[j_k] - y[i] + z[i] ))
template<int CO>
__global__ __launch_bounds__(256) void k_edgemax(const float* __restrict__ yz,
                                                 const int* __restrict__ idx,
                                                 const float* __restrict__ g,
                                                 const float* __restrict__ bb,
                                                 float* __restrict__ out) {
    constexpr int TPP = CO / 4;          // threads per point
    constexpr int PPB = 256 / TPP;       // points per block (same batch: 1024%PPB==0)
    const int t = threadIdx.x;
    const int p = t / TPP;
    const int cw = (t % TPP) * 4;
    const int i0 = blockIdx.x * PPB;
    const int bbase = (i0 >> 10) << 10;
    __shared__ int sidx[PPB][K_];
    for (int u = t; u < PPB * K_; u += 256) {
        int pp = u / K_, kk = u - pp * K_;
        sidx[pp][kk] = idx[(size_t)(i0 + pp) * K_ + kk];
    }
    __syncthreads();
    const int ig = i0 + p;
    float4 m = {-3e38f, -3e38f, -3e38f, -3e38f};
    #pragma unroll 4
    for (int k = 0; k < K_; k++) {
        const int jg = bbase + sidx[p][k];
        const float4 yv = *reinterpret_cast<const float4*>(&yz[(size_t)jg * 2 * CO + cw]);
        m.x = fmaxf(m.x, yv.x); m.y = fmaxf(m.y, yv.y);
        m.z = fmaxf(m.z, yv.z); m.w = fmaxf(m.w, yv.w);
    }
    const float4 yi = *reinterpret_cast<const float4*>(&yz[(size_t)ig * 2 * CO + cw]);
    const float4 zi = *reinterpret_cast<const float4*>(&yz[(size_t)ig * 2 * CO + CO + cw]);
    const float4 gv = *reinterpret_cast<const float4*>(&g[cw]);
    const float4 bv = *reinterpret_cast<const float4*>(&bb[cw]);
    float vals[4] = {m.x - yi.x + zi.x, m.y - yi.y + zi.y,
                     m.z - yi.z + zi.z, m.w - yi.w + zi.w};
    float gs[4] = {gv.x, gv.y, gv.z, gv.w};
    float bs[4] = {bv.x, bv.y, bv.z, bv.w};
    float4 o;
    float* op = &o.x;
    #pragma unroll
    for (int j = 0; j < 4; j++) {
        float h = vals[j] * (gs[j] * BN_SCALE) + bs[j];
        op[j] = h >= 0.f ? h : 0.2f * h;
    }
    *reinterpret_cast<float4*>(&out[(size_t)ig * CO + cw]) = o;
}

// ---------------------------------------------------------------- attention (per n, 8x8 per head)
template<int E>
__global__ __launch_bounds__(256) void k_attn(const float* __restrict__ qkv,
                                              float* __restrict__ o) {
    constexpr int H = 4, D = E / H, L = 8;
    const int n = blockIdx.x;
    const int t = threadIdx.x;
    const int h = t >> 6, lane = t & 63;
    __shared__ float sq[L][3 * E];
    __shared__ float so[L][E];
    for (int u = t; u < L * 3 * E; u += 256) {
        int l = u / (3 * E), r = u - l * (3 * E);
        sq[l][r] = qkv[(size_t)(l * N_ + n) * (3 * E) + r];
    }
    __syncthreads();
    const int l = lane >> 3, m = lane & 7;
    float s = 0.f;
    #pragma unroll 8
    for (int dd = 0; dd < D; dd++)
        s += sq[l][h * D + dd] * sq[m][E + h * D + dd];
    float mx = s;
    #pragma unroll
    for (int st = 1; st < 8; st <<= 1) mx = fmaxf(mx, __shfl_xor(mx, st, 64));
    float e = expf(s - mx);
    float sum = e;
    #pragma unroll
    for (int st = 1; st < 8; st <<= 1) sum += __shfl_xor(sum, st, 64);
    const float p = e / sum;
    float pm[8];
    #pragma unroll
    for (int mm = 0; mm < 8; mm++) pm[mm] = __shfl(p, (lane & 56) | mm, 64);
    #pragma unroll
    for (int j = 0; j < D / 8; j++) {
        const int dd = m + 8 * j;
        float a = 0.f;
        #pragma unroll
        for (int mm = 0; mm < 8; mm++) a += pm[mm] * sq[mm][2 * E + h * D + dd];
        so[l][h * D + dd] = a;
    }
    __syncthreads();
    for (int u = t; u < L * E; u += 256) {
        int l2 = u / E, e2 = u - l2 * E;
        o[(size_t)(l2 * N_ + n) * E + e2] = so[l2][e2];
    }
}

// ---------------------------------------------------------------- cat: [x1|x2|x3|x4] -> (8192, 512)
__global__ __launch_bounds__(256) void k_cat(const float* __restrict__ x1, const float* __restrict__ x2,
                                             const float* __restrict__ x3, const float* __restrict__ x4,
                                             float* __restrict__ cat) {
    int u = blockIdx.x * 256 + threadIdx.x;
    int p = u >> 9, c = u & 511;
    float v;
    if (c < 64)       v = x1[(size_t)p * 64 + c];
    else if (c < 128) v = x2[(size_t)p * 64 + (c - 64)];
    else if (c < 256) v = x3[(size_t)p * 128 + (c - 128)];
    else              v = x4[(size_t)p * 256 + (c - 256)];
    cat[u] = v;
}

// ---------------------------------------------------------------- pool (two-phase)
__global__ __launch_bounds__(256) void k_pool1(const float* __restrict__ h5,
                                               float* __restrict__ pmax,
                                               float* __restrict__ psum) {
    int c = blockIdx.x * 256 + threadIdx.x;   // 0..1023
    int b = blockIdx.y, ch = blockIdx.z;
    float mx = -3e38f, sm = 0.f;
    for (int n = ch * 128; n < ch * 128 + 128; n++) {
        float v = h5[((size_t)b * N_ + n) * 1024 + c];
        mx = fmaxf(mx, v); sm += v;
    }
    pmax[((size_t)b * 8 + ch) * 1024 + c] = mx;
    psum[((size_t)b * 8 + ch) * 1024 + c] = sm;
}

__global__ __launch_bounds__(256) void k_pool2(const float* __restrict__ pmax,
                                               const float* __restrict__ psum,
                                               float* __restrict__ feat) {
    int c = blockIdx.x * 256 + threadIdx.x;
    int b = blockIdx.y;
    float mx = -3e38f, sm = 0.f;
    #pragma unroll
    for (int ch = 0; ch < 8; ch++) {
        mx = fmaxf(mx, pmax[((size_t)b * 8 + ch) * 1024 + c]);
        sm += psum[((size_t)b * 8 + ch) * 1024 + c];
    }
    feat[b * 2048 + c] = mx;
    feat[b * 2048 + 1024 + c] = sm * (1.f / 1024.f);
}

// ---------------------------------------------------------------- FC head
// fc1: grid (8 oc, 8 b); 4-way split-K per output, LDS reduce.
__global__ __launch_bounds__(256) void k_fc1(const float* __restrict__ feat, const float* __restrict__ l1wT,
                                             const float* __restrict__ g6, const float* __restrict__ b6,
                                             float* __restrict__ f1) {
    int oc = blockIdx.x, b = blockIdx.y, t = threadIdx.x;
    __shared__ float fin[2048];
    __shared__ float psum[4][64];
    for (int u = t; u < 2048; u += 256) fin[u] = feat[b * 2048 + u];
    __syncthreads();
    int ol = t & 63, kc = t >> 6;
    int o = oc * 64 + ol;
    float acc = 0.f;
    for (int c = kc * 512; c < kc * 512 + 512; c++) acc += fin[c] * l1wT[(size_t)c * 512 + o];
    psum[kc][ol] = acc;
    __syncthreads();
    if (t < 64) {
        int oo = oc * 64 + t;
        float a = psum[0][t] + psum[1][t] + psum[2][t] + psum[3][t];
        float h = a * (g6[oo] * BN_SCALE) + b6[oo];
        f1[b * 512 + oo] = h >= 0.f ? h : 0.2f * h;
    }
}

__global__ __launch_bounds__(256) void k_fc2(const float* __restrict__ f1, const float* __restrict__ l2wT,
                                             const float* __restrict__ l2b,
                                             const float* __restrict__ g7, const float* __restrict__ b7,
                                             float* __restrict__ f2) {
    int b = blockIdx.x, t = threadIdx.x;
    __shared__ float fin[512];
    for (int u = t; u < 512; u += 256) fin[u] = f1[b * 512 + u];
    __syncthreads();
    if (t < 256) {
        int o = t;
        float acc = 0.f;
        for (int c = 0; c < 512; c++) acc += fin[c] * l2wT[(size_t)c * 256 + o];
        acc += l2b[o];
        float h = acc * (g7[o] * BN_SCALE) + b7[o];
        f2[b * 256 + o] = h >= 0.f ? h : 0.2f * h;
    }
}

__global__ __launch_bounds__(64) void k_fc3(const float* __restrict__ f2, const float* __restrict__ l3wT,
                                            const float* __restrict__ l3b,
                                            void* __restrict__ out, const int* __restrict__ flag) {
    int b = blockIdx.x, t = threadIdx.x;
    __shared__ float fin[256];
    for (int u = t; u < 256; u += 64) fin[u] = f2[b * 256 + u];
    __syncthreads();
    if (t < 40) {
        float acc = 0.f;
        for (int c = 0; c < 256; c++) acc += fin[c] * l3wT[(size_t)c * 40 + t];
        acc += l3b[t];
        if (*flag) ((__hip_bfloat16*)out)[b * 40 + t] = __float2bfloat16(acc);
        else       ((float*)out)[b * 40 + t] = acc;
    }
}

// ================================================================ host
extern "C" void kernel_launch(void* const* d_in, const int* in_sizes, int n_in,
                              void* d_out, int out_size, void* d_ws, size_t ws_size,
                              hipStream_t stream) {
    auto us = [&](int i) { return (const unsigned short*)d_in[i]; };

    float* ws = (float*)d_ws;
    size_t off = 0;
    auto A = [&](size_t n) { float* p = ws + off; off += (n + 3) & ~(size_t)3; return p; };
    float* xf0  = A((size_t)BN_ * 3);
    float* x1   = A((size_t)BN_ * 64);
    float* x2   = A((size_t)BN_ * 64);
    float* x3   = A((size_t)BN_ * 128);
    float* x4   = A((size_t)BN_ * 256);
    float* h5   = A((size_t)BN_ * 1024);   // also reused as pd scratch (8x1024x1024)
    float* feat = A(8 * 2048);
    float* f1   = A(8 * 512);
    float* f2   = A(8 * 256);
    float* xx   = A(BN_);
    int*   idx  = (int*)A((size_t)BN_ * K_);
    int*   flag = (int*)A(4);
    float* qkvw = A((size_t)BN_ * 768);   // qkv / edge-yz / cat scratch
    float* ow   = A((size_t)BN_ * 256);   // attn-out scratch
    float* pmax = A(8 * 8 * 1024);
    float* psum = A(8 * 8 * 1024);
    float* w1yz  = A(3 * 128);
    float* w2yz  = A(64 * 128);
    float* w3yz  = A(64 * 256);
    float* w4yz  = A(128 * 512);
    float* a1wiT = A(64 * 192);  float* a1woT = A(64 * 64);
    float* a2wiT = A(64 * 192);  float* a2woT = A(64 * 64);
    float* a3wiT = A(128 * 384); float* a3woT = A(128 * 128);
    float* a4wiT = A(256 * 768); float* a4woT = A(256 * 256);
    float* w5T   = A(512 * 1024);
    float* l1wT  = A(2048 * 512);
    float* l2wT  = A(512 * 256);
    float* l3wT  = A(256 * 40);
    // converted small vectors
    float* g1f = A(64);   float* b1f = A(64);
    float* g2f = A(64);   float* b2f = A(64);
    float* g3f = A(128);  float* b3f = A(128);
    float* g4f = A(256);  float* b4f = A(256);
    float* bi1 = A(192);  float* bo1 = A(64);
    float* bi2 = A(192);  float* bo2 = A(64);
    float* bi3 = A(384);  float* bo3 = A(128);
    float* bi4 = A(768);  float* bo4 = A(256);
    float* g5f = A(1024); float* b5f = A(1024);
    float* g6f = A(512);  float* b6f = A(512);
    float* l2bf = A(256);
    float* g7f = A(256);  float* b7f = A(256);
    float* l3bf = A(40);

    k_detect<<<1, 1, 0, stream>>>(us(2), us(5), us(8), us(11), us(30), us(33), us(37), flag);

    TList tl; int nb = 0; int k = 0;
    auto add = [&](int i, float* dst, int O, int I, int mode) {
        tl.p[k].src = d_in[i]; tl.p[k].dst = dst; tl.p[k].O = O; tl.p[k].I = I;
        tl.p[k].blk0 = nb; tl.p[k].mode = mode;
        nb += (O * I + 255) / 256; k++;
    };
    add(0,  xf0,   BN_ * 3, 1, 0);   // x convert (identity "transpose")
    add(1,  w1yz,  64, 6, 1);        // edge pair layouts
    add(4,  w2yz,  64, 128, 1);
    add(7,  w3yz,  128, 128, 1);
    add(10, w4yz,  256, 256, 1);
    add(13, a1wiT, 192, 64, 0);
    add(15, a1woT, 64, 64, 0);
    add(17, a2wiT, 192, 64, 0);
    add(19, a2woT, 64, 64, 0);
    add(21, a3wiT, 384, 128, 0);
    add(23, a3woT, 128, 128, 0);
    add(25, a4wiT, 768, 256, 0);
    add(27, a4woT, 256, 256, 0);
    add(29, w5T,   1024, 512, 0);
    add(32, l1wT,  512, 2048, 0);
    add(35, l2wT,  256, 512, 0);
    add(39, l3wT,  40, 256, 0);
    // vectors (identity convert)
    add(2,  g1f, 64, 1, 0);   add(3,  b1f, 64, 1, 0);
    add(5,  g2f, 64, 1, 0);   add(6,  b2f, 64, 1, 0);
    add(8,  g3f, 128, 1, 0);  add(9,  b3f, 128, 1, 0);
    add(11, g4f, 256, 1, 0);  add(12, b4f, 256, 1, 0);
    add(14, bi1, 192, 1, 0);  add(16, bo1, 64, 1, 0);
    add(18, bi2, 192, 1, 0);  add(20, bo2, 64, 1, 0);
    add(22, bi3, 384, 1, 0);  add(24, bo3, 128, 1, 0);
    add(26, bi4, 768, 1, 0);  add(28, bo4, 256, 1, 0);
    add(30, g5f, 1024, 1, 0); add(31, b5f, 1024, 1, 0);
    add(33, g6f, 512, 1, 0);  add(34, b6f, 512, 1, 0);
    add(36, l2bf, 256, 1, 0);
    add(37, g7f, 256, 1, 0);  add(38, b7f, 256, 1, 0);
    add(40, l3bf, 40, 1, 0);
    k_prep<<<nb, 256, 0, stream>>>(tl, k, flag);

    float* yzb = qkvw;  // edge [y|z] scratch (<= 8192x512)
    float* pd  = h5;    // pd scratch (h5 dead until conv5)
    const dim3 pdg(8, 16, 8);   // 128-row x 64-col tiles per batch

    // layer 1  (C=3 -> 64)
    k_norms<<<BN_ / 256, 256, 0, stream>>>(xf0, xx, 3);
    k_pd<3><<<pdg, 256, 0, stream>>>(xf0, pd);
    k_sel<<<BN_ / 4, 256, 0, stream>>>(pd, xx, idx);
    k_gemm<3, 128><<<dim3(64, 2), 256, 0, stream>>>(xf0, w1yz, nullptr, nullptr, yzb, 0, 1.f, nullptr, nullptr);
    k_edgemax<64><<<BN_ / 16, 256, 0, stream>>>(yzb, idx, g1f, b1f, x1);
    k_gemm<64, 192><<<dim3(64, 3), 256, 0, stream>>>(x1, a1wiT, bi1, nullptr, qkvw, 64, 0.25f, nullptr, nullptr);
    k_attn<64><<<N_, 256, 0, stream>>>(qkvw, ow);
    k_gemm<64, 64><<<dim3(64, 1), 256, 0, stream>>>(ow, a1woT, bo1, x1, x1, 0, 1.f, nullptr, nullptr);

    // layer 2  (C=64 -> 64)
    k_norms<<<BN_ / 256, 256, 0, stream>>>(x1, xx, 64);
    k_pd<64><<<pdg, 256, 0, stream>>>(x1, pd);
    k_sel<<<BN_ / 4, 256, 0, stream>>>(pd, xx, idx);
    k_gemm<64, 128><<<dim3(64, 2), 256, 0, stream>>>(x1, w2yz, nullptr, nullptr, yzb, 0, 1.f, nullptr, nullptr);
    k_edgemax<64><<<BN_ / 16, 256, 0, stream>>>(yzb, idx, g2f, b2f, x2);
    k_gemm<64, 192><<<dim3(64, 3), 256, 0, stream>>>(x2, a2wiT, bi2, nullptr, qkvw, 64, 0.25f, nullptr, nullptr);
    k_attn<64><<<N_, 256, 0, stream>>>(qkvw, ow);
    k_gemm<64, 64><<<dim3(64, 1), 256, 0, stream>>>(ow, a2woT, bo2, x2, x2, 0, 1.f, nullptr, nullptr);

    // layer 3  (C=64 -> 128)
    k_norms<<<BN_ / 256, 256, 0, stream>>>(x2, xx, 64);
    k_pd<64><<<pdg, 256, 0, stream>>>(x2, pd);
    k_sel<<<BN_ / 4, 256, 0, stream>>>(pd, xx, idx);
    k_gemm<64, 256><<<dim3(64, 4), 256, 0, stream>>>(x2, w3yz, nullptr, nullptr, yzb, 0, 1.f, nullptr, nullptr);
    k_edgemax<128><<<BN_ / 8, 256, 0, stream>>>(yzb, idx, g3f, b3f, x3);
    k_gemm<128, 384><<<dim3(64, 6), 256, 0, stream>>>(x3, a3wiT, bi3, nullptr, qkvw, 128, 0.17677669529663687f, nullptr, nullptr);
    k_attn<128><<<N_, 256, 0, stream>>>(qkvw, ow);
    k_gemm<128, 128><<<dim3(64, 2), 256, 0, stream>>>(ow, a3woT, bo3, x3, x3, 0, 1.f, nullptr, nullptr);

    // layer 4  (C=128 -> 256)
    k_norms<<<BN_ / 256, 256, 0, stream>>>(x3, xx, 128);
    k_pd<128><<<pdg, 256, 0, stream>>>(x3, pd);
    k_sel<<<BN_ / 4, 256, 0, stream>>>(pd, xx, idx);
    k_gemm<128, 512><<<dim3(64, 8), 256, 0, stream>>>(x3, w4yz, nullptr, nullptr, yzb, 0, 1.f, nullptr, nullptr);
    k_edgemax<256><<<BN_ / 4, 256, 0, stream>>>(yzb, idx, g4f, b4f, x4);
    k_gemm<256, 768><<<dim3(64, 12), 256, 0, stream>>>(x4, a4wiT, bi4, nullptr, qkvw, 256, 0.125f, nullptr, nullptr);
    k_attn<256><<<N_, 256, 0, stream>>>(qkvw, ow);
    k_gemm<256, 256><<<dim3(64, 4), 256, 0, stream>>>(ow, a4woT, bo4, x4, x4, 0, 1.f, nullptr, nullptr);

    // head: cat -> GEMM(BN+lrelu) -> pool -> FCs
    float* catb = qkvw;  // 8192x512 (free now)
    k_cat<<<(BN_ * 512) / 256, 256, 0, stream>>>(x1, x2, x3, x4, catb);
    k_gemm<512, 1024><<<dim3(64, 16), 256, 0, stream>>>(catb, w5T, nullptr, nullptr, h5, 0, 1.f, g5f, b5f);
    k_pool1<<<dim3(4, 8, 8), 256, 0, stream>>>(h5, pmax, psum);
    k_pool2<<<dim3(4, 8), 256, 0, stream>>>(pmax, psum, feat);
    k_fc1<<<dim3(8, 8), 256, 0, stream>>>(feat, l1wT, g6f, b6f, f1);
    k_fc2<<<8, 256, 0, stream>>>(f1, l2wT, l2bf, g7f, b7f, f2);
    k_fc3<<<8, 64, 0, stream>>>(f2, l3wT, l3bf, d_out, flag);
}

// Round 13
// 977.140 us; speedup vs baseline: 1.2935x; 1.2935x over previous
//
#include <hip/hip_runtime.h>
#include <hip/hip_bf16.h>

#define B_ 8
#define N_ 1024
#define K_ 20
#define BN_ (B_*N_)

#define BN_SCALE 0.9999950000374997f

typedef __attribute__((ext_vector_type(8))) short short8;
typedef __attribute__((ext_vector_type(4))) float f32x4;

__device__ __forceinline__ float US2F(unsigned short u) {
    union { unsigned u; float f; } c; c.u = ((unsigned)u) << 16; return c.f;
}
__device__ __forceinline__ unsigned short F2BF(float f) {   // RNE fp32->bf16
    union { float f; unsigned u; } c; c.f = f;
    unsigned r = c.u + 0x7FFF + ((c.u >> 16) & 1);
    return (unsigned short)(r >> 16);
}

// ---------------------------------------------------------------- dtype detect
__global__ void k_detect(const unsigned short* g1, const unsigned short* g2,
                         const unsigned short* g3, const unsigned short* g4,
                         const unsigned short* g5, const unsigned short* g6,
                         const unsigned short* g7, int* flag) {
    const unsigned short* gs[7] = {g1, g2, g3, g4, g5, g6, g7};
    int cnt = 0;
    for (int i = 0; i < 7; i++) {
        float v = US2F(gs[i][0]);
        if (v > 0.5f && v < 1.5f) cnt++;
    }
    *flag = (cnt >= 4) ? 1 : 0;   // 1 = bf16 inputs, 0 = fp32 inputs
}

// ---------------------------------------------------------------- prep
struct TPar { const void* src; float* dst; int O, I, blk0, mode; };
struct TList { TPar p[41]; };

__global__ __launch_bounds__(256) void k_prep(TList tl, int nent, const int* flag) {
    const int isbf = *flag;
    int blk = blockIdx.x;
    int wi = 0;
    for (int j = nent - 1; j >= 0; j--) { if (blk >= tl.p[j].blk0) { wi = j; break; } }
    const TPar p = tl.p[wi];
    int e = (blk - p.blk0) * 256 + threadIdx.x;
    int n = p.O * p.I;
    if (e >= n) return;
    int o = e / p.I, i = e - o * p.I;
    float v = isbf ? US2F(((const unsigned short*)p.src)[e])
                   : ((const float*)p.src)[e];
    if (p.mode == 0) {
        p.dst[(size_t)i * p.O + o] = v;
    } else {
        const int C = p.I >> 1;
        if (i < C) p.dst[(size_t)i * (2 * p.O) + o] = v;
        else       p.dst[(size_t)(i - C) * (2 * p.O) + p.O + o] = v;
    }
}

// ---------------------------------------------------------------- norms
__global__ __launch_bounds__(256) void k_norms(const float* __restrict__ xf,
                                               float* __restrict__ xx, int C) {
    int i = blockIdx.x * 256 + threadIdx.x;
    if (i >= BN_) return;
    const float* p = xf + (size_t)i * C;
    float s = 0.f;
    for (int c = 0; c < C; c++) s += p[c] * p[c];
    xx[i] = s;
}

// ---------------------------------------------------------------- kNN phase 1 (fp32: selection must not flip)
template<int C>
__global__ __launch_bounds__(256) void k_pd(const float* __restrict__ xf,
                                            float* __restrict__ pd) {
    const int b = blockIdx.z;
    const int rb = blockIdx.x * 64, cb = blockIdx.y * 64;
    const float* xb = xf + (size_t)b * N_ * C;
    const int t = threadIdx.x;
    __shared__ float As[32][65];   // As[k][m]
    __shared__ float Bs[32][65];   // Bs[k][j]
    float acc[4][4] = {};
    const int tm = (t >> 4) * 4, tn = (t & 15) * 4;
    for (int k0 = 0; k0 < C; k0 += 32) {
        __syncthreads();
        #pragma unroll
        for (int u = t; u < 64 * 32; u += 256) {
            int m = u >> 5, k = u & 31;
            float v;
            if constexpr (C % 32 == 0) v = xb[(size_t)(rb + m) * C + k0 + k];
            else v = (k0 + k < C) ? xb[(size_t)(rb + m) * C + k0 + k] : 0.f;
            As[k][m] = v;
        }
        #pragma unroll
        for (int u = t; u < 64 * 32; u += 256) {
            int j = u >> 5, k = u & 31;
            float v;
            if constexpr (C % 32 == 0) v = xb[(size_t)(cb + j) * C + k0 + k];
            else v = (k0 + k < C) ? xb[(size_t)(cb + j) * C + k0 + k] : 0.f;
            Bs[k][j] = v;
        }
        __syncthreads();
        #pragma unroll
        for (int k = 0; k < 32; k++) {
            const float4 av = *reinterpret_cast<const float4*>(&As[k][tm]);
            const float4 bv = *reinterpret_cast<const float4*>(&Bs[k][tn]);
            acc[0][0] += av.x * bv.x; acc[0][1] += av.x * bv.y; acc[0][2] += av.x * bv.z; acc[0][3] += av.x * bv.w;
            acc[1][0] += av.y * bv.x; acc[1][1] += av.y * bv.y; acc[1][2] += av.y * bv.z; acc[1][3] += av.y * bv.w;
            acc[2][0] += av.z * bv.x; acc[2][1] += av.z * bv.y; acc[2][2] += av.z * bv.z; acc[2][3] += av.z * bv.w;
            acc[3][0] += av.w * bv.x; acc[3][1] += av.w * bv.y; acc[3][2] += av.w * bv.z; acc[3][3] += av.w * bv.w;
        }
    }
    float* pdb = pd + (size_t)b * N_ * N_;
    #pragma unroll
    for (int j = 0; j < 4; j++) {
        const int row = rb + tm + j;
        #pragma unroll
        for (int jj = 0; jj < 4; jj++)
            pdb[(size_t)row * N_ + cb + tn + jj] = 2.f * acc[j][jj];
    }
}

// ---------------------------------------------------------------- kNN phase 2
__global__ __launch_bounds__(256) void k_sel(const float* __restrict__ pd,
                                             const float* __restrict__ xx,
                                             int* __restrict__ idx) {
    const int w = threadIdx.x >> 6, lane = threadIdx.x & 63;
    const int i = blockIdx.x * 4 + w;          // 0..8191
    const int b = i >> 10;
    const float* row = pd + (size_t)b * N_ * N_ + (size_t)(i & 1023) * N_;
    const float* xxb = xx + b * N_;
    float d[16];
    #pragma unroll
    for (int q = 0; q < 16; q++)
        d[q] = row[q * 64 + lane] - xxb[q * 64 + lane];
    int myj = 0;
    for (int kk = 0; kk < K_; kk++) {
        float v = d[0];
        #pragma unroll
        for (int u = 1; u < 16; u++) v = fmaxf(v, d[u]);
        #pragma unroll
        for (int s = 1; s < 64; s <<= 1) v = fmaxf(v, __shfl_xor(v, s, 64));
        int jw = -1;
        #pragma unroll
        for (int u = 0; u < 16; u++) {
            unsigned long long m = __ballot(d[u] == v);
            if (jw < 0 && m != 0ULL) jw = u * 64 + (int)__ffsll((long long)m) - 1;
        }
        if (jw < 0) jw = 0;
        if (lane == kk) myj = jw;
        const int wq = jw >> 6, wl = jw & 63;
        #pragma unroll
        for (int u = 0; u < 16; u++)
            if (u == wq && lane == wl) d[u] = -3e38f;
    }
    if (lane < K_) idx[(size_t)i * K_ + lane] = myj;
}

// ---------------------------------------------------------------- MFMA bf16 GEMM
// C[8192][NC] = A[8192][KD] @ Bt[KD][NC]; fp32 in/out, bf16 MFMA inside
// (fp32 accum). 64x64 tile, 4 waves x 2x2 mfma_f32_16x16x32_bf16 quadrants.
// LDS: [row|col][k] halves, stride 40 (80B: 16B-aligned b128 frag reads).
// Frag layouts (guide, HW-verified): A/B [dim=lane&15][k=(lane>>4)*8+j];
// C/D col=lane&15, row=(lane>>4)*4+reg.
template<int KD, int NC>
__global__ __launch_bounds__(256) void k_gemmb(const float* __restrict__ A,
                                               const float* __restrict__ Bt,
                                               const float* __restrict__ bias,
                                               const float* __restrict__ resid,
                                               float* __restrict__ Cout,
                                               int scale_cols, float qs,
                                               const float* __restrict__ gamma,
                                               const float* __restrict__ beta) {
    const int t = threadIdx.x;
    const int rb = blockIdx.x * 64, cb = blockIdx.y * 64;
    __shared__ __align__(16) unsigned short As[64 * 40];
    __shared__ __align__(16) unsigned short Bs[64 * 40];
    const int w = t >> 6, lane = t & 63;
    const int qr = (w & 1) * 32, qc = (w >> 1) * 32;
    f32x4 acc00 = {}, acc01 = {}, acc10 = {}, acc11 = {};
    for (int k0 = 0; k0 < KD; k0 += 32) {
        __syncthreads();
        // A tile: As[m][k], thread packs 2 consecutive k (float2 read, b32 write)
        #pragma unroll
        for (int u = t; u < 64 * 16; u += 256) {
            int m = u >> 4, kp = (u & 15) * 2;
            float f0, f1;
            if constexpr (KD % 32 == 0) {
                const float* ap = &A[(size_t)(rb + m) * KD + k0 + kp];
                f0 = ap[0]; f1 = ap[1];
            } else {
                f0 = (k0 + kp     < KD) ? A[(size_t)(rb + m) * KD + k0 + kp]     : 0.f;
                f1 = (k0 + kp + 1 < KD) ? A[(size_t)(rb + m) * KD + k0 + kp + 1] : 0.f;
            }
            unsigned pk = (unsigned)F2BF(f0) | ((unsigned)F2BF(f1) << 16);
            *reinterpret_cast<unsigned*>(&As[m * 40 + kp]) = pk;
        }
        // B tile: Bs[c][k] from Bt[k][c] (coalesced in c, 2 k per thread)
        #pragma unroll
        for (int u = t; u < 64 * 16; u += 256) {
            int kp = (u >> 6) * 2, c = u & 63;
            float f0, f1;
            if constexpr (KD % 32 == 0) {
                f0 = Bt[(size_t)(k0 + kp) * NC + cb + c];
                f1 = Bt[(size_t)(k0 + kp + 1) * NC + cb + c];
            } else {
                f0 = (k0 + kp     < KD) ? Bt[(size_t)(k0 + kp)     * NC + cb + c] : 0.f;
                f1 = (k0 + kp + 1 < KD) ? Bt[(size_t)(k0 + kp + 1) * NC + cb + c] : 0.f;
            }
            unsigned pk = (unsigned)F2BF(f0) | ((unsigned)F2BF(f1) << 16);
            *reinterpret_cast<unsigned*>(&Bs[c * 40 + kp]) = pk;
        }
        __syncthreads();
        const int fr = lane & 15, fq = (lane >> 4) * 8;
        const short8 a0 = *reinterpret_cast<const short8*>(&As[(qr + fr) * 40 + fq]);
        const short8 a1 = *reinterpret_cast<const short8*>(&As[(qr + 16 + fr) * 40 + fq]);
        const short8 b0 = *reinterpret_cast<const short8*>(&Bs[(qc + fr) * 40 + fq]);
        const short8 b1 = *reinterpret_cast<const short8*>(&Bs[(qc + 16 + fr) * 40 + fq]);
        acc00 = __builtin_amdgcn_mfma_f32_16x16x32_bf16(a0, b0, acc00, 0, 0, 0);
        acc01 = __builtin_amdgcn_mfma_f32_16x16x32_bf16(a0, b1, acc01, 0, 0, 0);
        acc10 = __builtin_amdgcn_mfma_f32_16x16x32_bf16(a1, b0, acc10, 0, 0, 0);
        acc11 = __builtin_amdgcn_mfma_f32_16x16x32_bf16(a1, b1, acc11, 0, 0, 0);
    }
    const int cr = (lane >> 4) * 4, cc = lane & 15;
    #pragma unroll
    for (int i = 0; i < 2; i++) {
        #pragma unroll
        for (int j = 0; j < 2; j++) {
            const f32x4 av = (i == 0) ? (j == 0 ? acc00 : acc01) : (j == 0 ? acc10 : acc11);
            #pragma unroll
            for (int r = 0; r < 4; r++) {
                const int row = rb + qr + i * 16 + cr + r;
                const int col = cb + qc + j * 16 + cc;
                float v = av[r] + (bias ? bias[col] : 0.f);
                if (col < scale_cols) v *= qs;
                if (resid) v += resid[(size_t)row * NC + col];
                if (gamma) {
                    v = v * (gamma[col] * BN_SCALE) + beta[col];
                    v = v >= 0.f ? v : 0.2f * v;
                }
                Cout[(size_t)row * NC + col] = v;
            }
        }
    }
}

// ---------------------------------------------------------------- EdgeConv epilogue
template<int CO>
__global__ __launch_bounds__(256) void k_edgemax(const float* __restrict__ yz,
                                                 const int* __restrict__ idx,
                                                 const float* __restrict__ g,
                                                 const float* __restrict__ bb,
                                                 float* __restrict__ out) {
    constexpr int TPP = CO / 4;
    constexpr int PPB = 256 / TPP;
    const int t = threadIdx.x;
    const int p = t / TPP;
    const int cw = (t % TPP) * 4;
    const int i0 = blockIdx.x * PPB;
    const int bbase = (i0 >> 10) << 10;
    __shared__ int sidx[PPB][K_];
    for (int u = t; u < PPB * K_; u += 256) {
        int pp = u / K_, kk = u - pp * K_;
        sidx[pp][kk] = idx[(size_t)(i0 + pp) * K_ + kk];
    }
    __syncthreads();
    const int ig = i0 + p;
    float4 m = {-3e38f, -3e38f, -3e38f, -3e38f};
    #pragma unroll 4
    for (int k = 0; k < K_; k++) {
        const int jg = bbase + sidx[p][k];
        const float4 yv = *reinterpret_cast<const float4*>(&yz[(size_t)jg * 2 * CO + cw]);
        m.x = fmaxf(m.x, yv.x); m.y = fmaxf(m.y, yv.y);
        m.z = fmaxf(m.z, yv.z); m.w = fmaxf(m.w, yv.w);
    }
    const float4 yi = *reinterpret_cast<const float4*>(&yz[(size_t)ig * 2 * CO + cw]);
    const float4 zi = *reinterpret_cast<const float4*>(&yz[(size_t)ig * 2 * CO + CO + cw]);
    const float4 gv = *reinterpret_cast<const float4*>(&g[cw]);
    const float4 bv = *reinterpret_cast<const float4*>(&bb[cw]);
    float vals[4] = {m.x - yi.x + zi.x, m.y - yi.y + zi.y,
                     m.z - yi.z + zi.z, m.w - yi.w + zi.w};
    float gs[4] = {gv.x, gv.y, gv.z, gv.w};
    float bs[4] = {bv.x, bv.y, bv.z, bv.w};
    float4 o;
    float* op = &o.x;
    #pragma unroll
    for (int j = 0; j < 4; j++) {
        float h = vals[j] * (gs[j] * BN_SCALE) + bs[j];
        op[j] = h >= 0.f ? h : 0.2f * h;
    }
    *reinterpret_cast<float4*>(&out[(size_t)ig * CO + cw]) = o;
}

// ---------------------------------------------------------------- attention
template<int E>
__global__ __launch_bounds__(256) void k_attn(const float* __restrict__ qkv,
                                              float* __restrict__ o) {
    constexpr int H = 4, D = E / H, L = 8;
    const int n = blockIdx.x;
    const int t = threadIdx.x;
    const int h = t >> 6, lane = t & 63;
    __shared__ float sq[L][3 * E];
    __shared__ float so[L][E];
    for (int u = t; u < L * 3 * E; u += 256) {
        int l = u / (3 * E), r = u - l * (3 * E);
        sq[l][r] = qkv[(size_t)(l * N_ + n) * (3 * E) + r];
    }
    __syncthreads();
    const int l = lane >> 3, m = lane & 7;
    float s = 0.f;
    #pragma unroll 8
    for (int dd = 0; dd < D; dd++)
        s += sq[l][h * D + dd] * sq[m][E + h * D + dd];
    float mx = s;
    #pragma unroll
    for (int st = 1; st < 8; st <<= 1) mx = fmaxf(mx, __shfl_xor(mx, st, 64));
    float e = expf(s - mx);
    float sum = e;
    #pragma unroll
    for (int st = 1; st < 8; st <<= 1) sum += __shfl_xor(sum, st, 64);
    const float p = e / sum;
    float pm[8];
    #pragma unroll
    for (int mm = 0; mm < 8; mm++) pm[mm] = __shfl(p, (lane & 56) | mm, 64);
    #pragma unroll
    for (int j = 0; j < D / 8; j++) {
        const int dd = m + 8 * j;
        float a = 0.f;
        #pragma unroll
        for (int mm = 0; mm < 8; mm++) a += pm[mm] * sq[mm][2 * E + h * D + dd];
        so[l][h * D + dd] = a;
    }
    __syncthreads();
    for (int u = t; u < L * E; u += 256) {
        int l2 = u / E, e2 = u - l2 * E;
        o[(size_t)(l2 * N_ + n) * E + e2] = so[l2][e2];
    }
}

// ---------------------------------------------------------------- cat
__global__ __launch_bounds__(256) void k_cat(const float* __restrict__ x1, const float* __restrict__ x2,
                                             const float* __restrict__ x3, const float* __restrict__ x4,
                                             float* __restrict__ cat) {
    int u = blockIdx.x * 256 + threadIdx.x;
    int p = u >> 9, c = u & 511;
    float v;
    if (c < 64)       v = x1[(size_t)p * 64 + c];
    else if (c < 128) v = x2[(size_t)p * 64 + (c - 64)];
    else if (c < 256) v = x3[(size_t)p * 128 + (c - 128)];
    else              v = x4[(size_t)p * 256 + (c - 256)];
    cat[u] = v;
}

// ---------------------------------------------------------------- pool (two-phase)
__global__ __launch_bounds__(256) void k_pool1(const float* __restrict__ h5,
                                               float* __restrict__ pmax,
                                               float* __restrict__ psum) {
    int c = blockIdx.x * 256 + threadIdx.x;
    int b = blockIdx.y, ch = blockIdx.z;
    float mx = -3e38f, sm = 0.f;
    for (int n = ch * 128; n < ch * 128 + 128; n++) {
        float v = h5[((size_t)b * N_ + n) * 1024 + c];
        mx = fmaxf(mx, v); sm += v;
    }
    pmax[((size_t)b * 8 + ch) * 1024 + c] = mx;
    psum[((size_t)b * 8 + ch) * 1024 + c] = sm;
}

__global__ __launch_bounds__(256) void k_pool2(const float* __restrict__ pmax,
                                               const float* __restrict__ psum,
                                               float* __restrict__ feat) {
    int c = blockIdx.x * 256 + threadIdx.x;
    int b = blockIdx.y;
    float mx = -3e38f, sm = 0.f;
    #pragma unroll
    for (int ch = 0; ch < 8; ch++) {
        mx = fmaxf(mx, pmax[((size_t)b * 8 + ch) * 1024 + c]);
        sm += psum[((size_t)b * 8 + ch) * 1024 + c];
    }
    feat[b * 2048 + c] = mx;
    feat[b * 2048 + 1024 + c] = sm * (1.f / 1024.f);
}

// ---------------------------------------------------------------- FC head
__global__ __launch_bounds__(256) void k_fc1(const float* __restrict__ feat, const float* __restrict__ l1wT,
                                             const float* __restrict__ g6, const float* __restrict__ b6,
                                             float* __restrict__ f1) {
    int oc = blockIdx.x, b = blockIdx.y, t = threadIdx.x;
    __shared__ float fin[2048];
    __shared__ float psum[4][64];
    for (int u = t; u < 2048; u += 256) fin[u] = feat[b * 2048 + u];
    __syncthreads();
    int ol = t & 63, kc = t >> 6;
    int o = oc * 64 + ol;
    float acc = 0.f;
    for (int c = kc * 512; c < kc * 512 + 512; c++) acc += fin[c] * l1wT[(size_t)c * 512 + o];
    psum[kc][ol] = acc;
    __syncthreads();
    if (t < 64) {
        int oo = oc * 64 + t;
        float a = psum[0][t] + psum[1][t] + psum[2][t] + psum[3][t];
        float h = a * (g6[oo] * BN_SCALE) + b6[oo];
        f1[b * 512 + oo] = h >= 0.f ? h : 0.2f * h;
    }
}

__global__ __launch_bounds__(256) void k_fc2(const float* __restrict__ f1, const float* __restrict__ l2wT,
                                             const float* __restrict__ l2b,
                                             const float* __restrict__ g7, const float* __restrict__ b7,
                                             float* __restrict__ f2) {
    int b = blockIdx.x, t = threadIdx.x;
    __shared__ float fin[512];
    for (int u = t; u < 512; u += 256) fin[u] = f1[b * 512 + u];
    __syncthreads();
    if (t < 256) {
        int o = t;
        float acc = 0.f;
        for (int c = 0; c < 512; c++) acc += fin[c] * l2wT[(size_t)c * 256 + o];
        acc += l2b[o];
        float h = acc * (g7[o] * BN_SCALE) + b7[o];
        f2[b * 256 + o] = h >= 0.f ? h : 0.2f * h;
    }
}

__global__ __launch_bounds__(64) void k_fc3(const float* __restrict__ f2, const float* __restrict__ l3wT,
                                            const float* __restrict__ l3b,
                                            void* __restrict__ out, const int* __restrict__ flag) {
    int b = blockIdx.x, t = threadIdx.x;
    __shared__ float fin[256];
    for (int u = t; u < 256; u += 64) fin[u] = f2[b * 256 + u];
    __syncthreads();
    if (t < 40) {
        float acc = 0.f;
        for (int c = 0; c < 256; c++) acc += fin[c] * l3wT[(size_t)c * 40 + t];
        acc += l3b[t];
        if (*flag) ((__hip_bfloat16*)out)[b * 40 + t] = __float2bfloat16(acc);
        else       ((float*)out)[b * 40 + t] = acc;
    }
}

// ================================================================ host
extern "C" void kernel_launch(void* const* d_in, const int* in_sizes, int n_in,
                              void* d_out, int out_size, void* d_ws, size_t ws_size,
                              hipStream_t stream) {
    auto us = [&](int i) { return (const unsigned short*)d_in[i]; };

    float* ws = (float*)d_ws;
    size_t off = 0;
    auto A = [&](size_t n) { float* p = ws + off; off += (n + 3) & ~(size_t)3; return p; };
    float* xf0  = A((size_t)BN_ * 3);
    float* x1   = A((size_t)BN_ * 64);
    float* x2   = A((size_t)BN_ * 64);
    float* x3   = A((size_t)BN_ * 128);
    float* x4   = A((size_t)BN_ * 256);
    float* h5   = A((size_t)BN_ * 1024);   // also pd scratch
    float* feat = A(8 * 2048);
    float* f1   = A(8 * 512);
    float* f2   = A(8 * 256);
    float* xx   = A(BN_);
    int*   idx  = (int*)A((size_t)BN_ * K_);
    int*   flag = (int*)A(4);
    float* qkvw = A((size_t)BN_ * 768);
    float* ow   = A((size_t)BN_ * 256);
    float* pmax = A(8 * 8 * 1024);
    float* psum = A(8 * 8 * 1024);
    float* w1yz  = A(3 * 128);
    float* w2yz  = A(64 * 128);
    float* w3yz  = A(64 * 256);
    float* w4yz  = A(128 * 512);
    float* a1wiT = A(64 * 192);  float* a1woT = A(64 * 64);
    float* a2wiT = A(64 * 192);  float* a2woT = A(64 * 64);
    float* a3wiT = A(128 * 384); float* a3woT = A(128 * 128);
    float* a4wiT = A(256 * 768); float* a4woT = A(256 * 256);
    float* w5T   = A(512 * 1024);
    float* l1wT  = A(2048 * 512);
    float* l2wT  = A(512 * 256);
    float* l3wT  = A(256 * 40);
    float* g1f = A(64);   float* b1f = A(64);
    float* g2f = A(64);   float* b2f = A(64);
    float* g3f = A(128);  float* b3f = A(128);
    float* g4f = A(256);  float* b4f = A(256);
    float* bi1 = A(192);  float* bo1 = A(64);
    float* bi2 = A(192);  float* bo2 = A(64);
    float* bi3 = A(384);  float* bo3 = A(128);
    float* bi4 = A(768);  float* bo4 = A(256);
    float* g5f = A(1024); float* b5f = A(1024);
    float* g6f = A(512);  float* b6f = A(512);
    float* l2bf = A(256);
    float* g7f = A(256);  float* b7f = A(256);
    float* l3bf = A(40);

    k_detect<<<1, 1, 0, stream>>>(us(2), us(5), us(8), us(11), us(30), us(33), us(37), flag);

    TList tl; int nb = 0; int k = 0;
    auto add = [&](int i, float* dst, int O, int I, int mode) {
        tl.p[k].src = d_in[i]; tl.p[k].dst = dst; tl.p[k].O = O; tl.p[k].I = I;
        tl.p[k].blk0 = nb; tl.p[k].mode = mode;
        nb += (O * I + 255) / 256; k++;
    };
    add(0,  xf0,   BN_ * 3, 1, 0);
    add(1,  w1yz,  64, 6, 1);
    add(4,  w2yz,  64, 128, 1);
    add(7,  w3yz,  128, 128, 1);
    add(10, w4yz,  256, 256, 1);
    add(13, a1wiT, 192, 64, 0);
    add(15, a1woT, 64, 64, 0);
    add(17, a2wiT, 192, 64, 0);
    add(19, a2woT, 64, 64, 0);
    add(21, a3wiT, 384, 128, 0);
    add(23, a3woT, 128, 128, 0);
    add(25, a4wiT, 768, 256, 0);
    add(27, a4woT, 256, 256, 0);
    add(29, w5T,   1024, 512, 0);
    add(32, l1wT,  512, 2048, 0);
    add(35, l2wT,  256, 512, 0);
    add(39, l3wT,  40, 256, 0);
    add(2,  g1f, 64, 1, 0);   add(3,  b1f, 64, 1, 0);
    add(5,  g2f, 64, 1, 0);   add(6,  b2f, 64, 1, 0);
    add(8,  g3f, 128, 1, 0);  add(9,  b3f, 128, 1, 0);
    add(11, g4f, 256, 1, 0);  add(12, b4f, 256, 1, 0);
    add(14, bi1, 192, 1, 0);  add(16, bo1, 64, 1, 0);
    add(18, bi2, 192, 1, 0);  add(20, bo2, 64, 1, 0);
    add(22, bi3, 384, 1, 0);  add(24, bo3, 128, 1, 0);
    add(26, bi4, 768, 1, 0);  add(28, bo4, 256, 1, 0);
    add(30, g5f, 1024, 1, 0); add(31, b5f, 1024, 1, 0);
    add(33, g6f, 512, 1, 0);  add(34, b6f, 512, 1, 0);
    add(36, l2bf, 256, 1, 0);
    add(37, g7f, 256, 1, 0);  add(38, b7f, 256, 1, 0);
    add(40, l3bf, 40, 1, 0);
    k_prep<<<nb, 256, 0, stream>>>(tl, k, flag);

    float* yzb = qkvw;
    float* pd  = h5;
    const dim3 pdg(16, 16, 8);

    // layer 1  (C=3 -> 64)
    k_norms<<<BN_ / 256, 256, 0, stream>>>(xf0, xx, 3);
    k_pd<3><<<pdg, 256, 0, stream>>>(xf0, pd);
    k_sel<<<BN_ / 4, 256, 0, stream>>>(pd, xx, idx);
    k_gemmb<3, 128><<<dim3(128, 2), 256, 0, stream>>>(xf0, w1yz, nullptr, nullptr, yzb, 0, 1.f, nullptr, nullptr);
    k_edgemax<64><<<BN_ / 16, 256, 0, stream>>>(yzb, idx, g1f, b1f, x1);
    k_gemmb<64, 192><<<dim3(128, 3), 256, 0, stream>>>(x1, a1wiT, bi1, nullptr, qkvw, 64, 0.25f, nullptr, nullptr);
    k_attn<64><<<N_, 256, 0, stream>>>(qkvw, ow);
    k_gemmb<64, 64><<<dim3(128, 1), 256, 0, stream>>>(ow, a1woT, bo1, x1, x1, 0, 1.f, nullptr, nullptr);

    // layer 2  (C=64 -> 64)
    k_norms<<<BN_ / 256, 256, 0, stream>>>(x1, xx, 64);
    k_pd<64><<<pdg, 256, 0, stream>>>(x1, pd);
    k_sel<<<BN_ / 4, 256, 0, stream>>>(pd, xx, idx);
    k_gemmb<64, 128><<<dim3(128, 2), 256, 0, stream>>>(x1, w2yz, nullptr, nullptr, yzb, 0, 1.f, nullptr, nullptr);
    k_edgemax<64><<<BN_ / 16, 256, 0, stream>>>(yzb, idx, g2f, b2f, x2);
    k_gemmb<64, 192><<<dim3(128, 3), 256, 0, stream>>>(x2, a2wiT, bi2, nullptr, qkvw, 64, 0.25f, nullptr, nullptr);
    k_attn<64><<<N_, 256, 0, stream>>>(qkvw, ow);
    k_gemmb<64, 64><<<dim3(128, 1), 256, 0, stream>>>(ow, a2woT, bo2, x2, x2, 0, 1.f, nullptr, nullptr);

    // layer 3  (C=64 -> 128)
    k_norms<<<BN_ / 256, 256, 0, stream>>>(x2, xx, 64);
    k_pd<64><<<pdg, 256, 0, stream>>>(x2, pd);
    k_sel<<<BN_ / 4, 256, 0, stream>>>(pd, xx, idx);
    k_gemmb<64, 256><<<dim3(128, 4), 256, 0, stream>>>(x2, w3yz, nullptr, nullptr, yzb, 0, 1.f, nullptr, nullptr);
    k_edgemax<128><<<BN_ / 8, 256, 0, stream>>>(yzb, idx, g3f, b3f, x3);
    k_gemmb<128, 384><<<dim3(128, 6), 256, 0, stream>>>(x3, a3wiT, bi3, nullptr, qkvw, 128, 0.17677669529663687f, nullptr, nullptr);
    k_attn<128><<<N_, 256, 0, stream>>>(qkvw, ow);
    k_gemmb<128, 128><<<dim3(128, 2), 256, 0, stream>>>(ow, a3woT, bo3, x3, x3, 0, 1.f, nullptr, nullptr);

    // layer 4  (C=128 -> 256)
    k_norms<<<BN_ / 256, 256, 0, stream>>>(x3, xx, 128);
    k_pd<128><<<pdg, 256, 0, stream>>>(x3, pd);
    k_sel<<<BN_ / 4, 256, 0, stream>>>(pd, xx, idx);
    k_gemmb<128, 512><<<dim3(128, 8), 256, 0, stream>>>(x3, w4yz, nullptr, nullptr, yzb, 0, 1.f, nullptr, nullptr);
    k_edgemax<256><<<BN_ / 4, 256, 0, stream>>>(yzb, idx, g4f, b4f, x4);
    k_gemmb<256, 768><<<dim3(128, 12), 256, 0, stream>>>(x4, a4wiT, bi4, nullptr, qkvw, 256, 0.125f, nullptr, nullptr);
    k_attn<256><<<N_, 256, 0, stream>>>(qkvw, ow);
    k_gemmb<256, 256><<<dim3(128, 4), 256, 0, stream>>>(ow, a4woT, bo4, x4, x4, 0, 1.f, nullptr, nullptr);

    // head
    float* catb = qkvw;
    k_cat<<<(BN_ * 512) / 256, 256, 0, stream>>>(x1, x2, x3, x4, catb);
    k_gemmb<512, 1024><<<dim3(128, 16), 256, 0, stream>>>(catb, w5T, nullptr, nullptr, h5, 0, 1.f, g5f, b5f);
    k_pool1<<<dim3(4, 8, 8), 256, 0, stream>>>(h5, pmax, psum);
    k_pool2<<<dim3(4, 8), 256, 0, stream>>>(pmax, psum, feat);
    k_fc1<<<dim3(8, 8), 256, 0, stream>>>(feat, l1wT, g6f, b6f, f1);
    k_fc2<<<8, 256, 0, stream>>>(f1, l2wT, l2bf, g7f, b7f, f2);
    k_fc3<<<8, 64, 0, stream>>>(f2, l3wT, l3bf, d_out, flag);
}